// Round 14
// baseline (169.444 us; speedup 1.0000x reference)
//
#include <hip/hip_runtime.h>
#include <hip/hip_bf16.h>
#include <stdint.h>

// B=1, S=4096, D=1024, H=16, HD=64. I/O = float32; internal compute bf16 MFMA.
constexpr int SEQ  = 4096;
constexpr int DIM  = 1024;
constexpr int NH   = 16;
constexpr int HDM  = 64;

typedef __bf16 bf16;
typedef __attribute__((ext_vector_type(4)))  float  f32x4;
typedef __attribute__((ext_vector_type(16))) float  f32x16;
typedef __attribute__((ext_vector_type(8)))  __bf16 bf16x8;
typedef __attribute__((ext_vector_type(4)))  __bf16 bf16x4;
typedef __attribute__((ext_vector_type(4)))  unsigned u32x4;

__device__ __forceinline__ void gload_lds16(const bf16* g, bf16* l) {
  __builtin_amdgcn_global_load_lds(
      (const __attribute__((address_space(1))) unsigned int*)g,
      (__attribute__((address_space(3))) unsigned int*)l, 16, 0, 0);
}

__device__ __forceinline__ unsigned pack2(float lo, float hi) {
  unsigned short a = __builtin_bit_cast(unsigned short, (bf16)lo);
  unsigned short b = __builtin_bit_cast(unsigned short, (bf16)hi);
  return ((unsigned)b << 16) | a;
}

// f32 -> bf16 for x + the 4 weight matrices. blockIdx.y selects tensor.
__global__ void cvt5(const float* __restrict__ x,  const float* __restrict__ wq,
                     const float* __restrict__ wk, const float* __restrict__ wv,
                     const float* __restrict__ wo,
                     bf16* __restrict__ xb,  bf16* __restrict__ wqb,
                     bf16* __restrict__ wkb, bf16* __restrict__ wvb,
                     bf16* __restrict__ wob) {
  const float* in; bf16* out; int n;
  switch (blockIdx.y) {
    case 0:  in = x;  out = xb;  n = SEQ * DIM; break;
    case 1:  in = wq; out = wqb; n = DIM * DIM; break;
    case 2:  in = wk; out = wkb; n = DIM * DIM; break;
    case 3:  in = wv; out = wvb; n = DIM * DIM; break;
    default: in = wo; out = wob; n = DIM * DIM; break;
  }
  const int i = (blockIdx.x * blockDim.x + threadIdx.x) * 8;
  if (i >= n) return;
  f32x4 a = *(const f32x4*)(in + i);
  f32x4 b = *(const f32x4*)(in + i + 4);
  bf16x8 o;
#pragma unroll
  for (int j = 0; j < 4; ++j) { o[j] = (bf16)a[j]; o[j + 4] = (bf16)b[j]; }
  *(bf16x8*)(out + i) = o;
}

// ------------- QKV GEMM: 128x128 tile, C = (A W^T) * sc --------------------
template <typename OutT, bool QKV>
__global__ __launch_bounds__(256, 2)
void gemm_xwt(const bf16* __restrict__ A,
              const bf16* __restrict__ W0, const bf16* __restrict__ W1,
              const bf16* __restrict__ W2,
              OutT* __restrict__ C0, OutT* __restrict__ C1, OutT* __restrict__ C2) {
  const bf16* W;
  OutT* C;
  float sc = 1.0f;
  if (QKV) {
    const int z = blockIdx.z;
    W = (z == 0) ? W0 : (z == 1) ? W1 : W2;
    C = (z == 0) ? C0 : (z == 1) ? C1 : C2;
    if (z == 0) sc = 0.18033688011112042f;  // 0.125 * log2(e)
  } else {
    W = W0; C = C0;
  }
  __shared__ bf16 As[128 * 32];
  __shared__ bf16 Bs[128 * 32];
  const int tid = threadIdx.x;
  const int w   = tid >> 6;
  const int l   = tid & 63;
  const int l15 = l & 15, lhi = l >> 4;
  const int wr  = w >> 1, wc = w & 1;
  const int row0 = blockIdx.y * 128;
  const int col0 = blockIdx.x * 128;

  f32x4 acc[4][4] = {};

  const int srow = w * 32 + (l >> 2);
  const int scol = (l & 3) * 8;
  const bf16* gA = A + (size_t)(row0 + srow) * DIM + scol;
  const bf16* gB = W + (size_t)(col0 + srow) * DIM + scol;
  bf16* lA = As + srow * 32 + scol;
  bf16* lB = Bs + srow * 32 + scol;

  for (int k0 = 0; k0 < DIM; k0 += 32) {
    __syncthreads();
    gload_lds16(gA + k0,            lA);
    gload_lds16(gA + k0 + 16 * DIM, lA + 16 * 32);
    gload_lds16(gB + k0,            lB);
    gload_lds16(gB + k0 + 16 * DIM, lB + 16 * 32);
    __syncthreads();
    bf16x8 af[4], bf_[4];
#pragma unroll
    for (int m = 0; m < 4; ++m)
      af[m] = *(const bf16x8*)(As + (wr * 64 + m * 16 + l15) * 32 + lhi * 8);
#pragma unroll
    for (int n = 0; n < 4; ++n)
      bf_[n] = *(const bf16x8*)(Bs + (wc * 64 + n * 16 + l15) * 32 + lhi * 8);
#pragma unroll
    for (int m = 0; m < 4; ++m)
#pragma unroll
      for (int n = 0; n < 4; ++n)
        acc[m][n] = __builtin_amdgcn_mfma_f32_16x16x32_bf16(af[m], bf_[n], acc[m][n], 0, 0, 0);
  }

#pragma unroll
  for (int m = 0; m < 4; ++m)
#pragma unroll
    for (int n = 0; n < 4; ++n)
#pragma unroll
      for (int r = 0; r < 4; ++r) {
        const int row = row0 + wr * 64 + m * 16 + lhi * 4 + r;
        const int col = col0 + wc * 64 + n * 16 + l15;
        C[(size_t)row * DIM + col] = (OutT)(acc[m][n][r] * sc);
      }
}

// --------------- V transpose: Vt[d][s] = Vs[s][d]  (once) -------------------
__global__ __launch_bounds__(256)
void transpose_v(const bf16* __restrict__ Vs, bf16* __restrict__ Vt) {
  __shared__ bf16 t[64][72];
  const int st = blockIdx.x * 64;
  const int dt = blockIdx.y * 64;
  const int tid = threadIdx.x;
  const int r  = tid >> 2;
  const int c0 = (tid & 3) * 16;
  bf16x8 a = *(const bf16x8*)(Vs + (size_t)(st + r) * DIM + dt + c0);
  bf16x8 b = *(const bf16x8*)(Vs + (size_t)(st + r) * DIM + dt + c0 + 8);
#pragma unroll
  for (int j = 0; j < 8; ++j) { t[r][c0 + j] = a[j]; t[r][c0 + 8 + j] = b[j]; }
  __syncthreads();
  const int d  = tid >> 2;
  const int s0 = (tid & 3) * 16;
  bf16x8 o1, o2;
#pragma unroll
  for (int j = 0; j < 8; ++j) { o1[j] = t[s0 + j][d]; o2[j] = t[s0 + 8 + j][d]; }
  bf16* dst = Vt + (size_t)(dt + d) * SEQ + st + s0;
  *(bf16x8*)(dst)     = o1;
  *(bf16x8*)(dst + 8) = o2;
}

// ---- Causal flash attention: 4-way inter-block KV split, FIXED-m softmax ----
// (r12 body: single accumulators — dual-acc raised VGPR 80->92 and cost a
//  wave/SIMD of occupancy, net -12% [round 13].)
__global__ __launch_bounds__(256, 2)
void attn_fwd(const bf16* __restrict__ Qg, const bf16* __restrict__ Kg,
              const bf16* __restrict__ Vt,
              bf16* __restrict__ P0, bf16* __restrict__ P1,
              bf16* __restrict__ P2, bf16* __restrict__ P3,
              float* __restrict__ ms) {
  __shared__ bf16 Kl[2][8][64][8];   // 16 KB
  __shared__ bf16 Vl[2][8][64][8];   // 16 KB
  const int tid = threadIdx.x;
  const int wv  = tid >> 6;
  const int l   = tid & 63;
  const int l31 = l & 31;
  const int hi  = l >> 5;
  const int bid = blockIdx.x;
  const int s   = bid & 3;
  const int bh  = bid >> 2;
  const int b   = 31 - (bh >> 4);        // big q-tiles dispatch first
  const int h   = bh & 15;
  const int qb0 = b * 128;
  const int hc  = h * HDM;
  const int tmaxb = 2 * b + 1;           // block-level last KV tile
  const int tdiag = 2 * b + (wv >> 1);   // this wave's diagonal tile
  const int qg  = qb0 + wv * 32 + l31;
  bf16* Po = (s == 0) ? P0 : (s == 1) ? P1 : (s == 2) ? P2 : P3;

  // Q B-frags (pre-scaled by 0.125*log2e in the Q-GEMM epilogue)
  bf16x8 qf[4];
#pragma unroll
  for (int ks = 0; ks < 4; ++ks)
    qf[ks] = *(const bf16x8*)(Qg + (size_t)qg * DIM + hc + ks * 16 + hi * 8);

  f32x16 ot0 = {}, ot1 = {};
  float sacc[8] = {};

  auto stage = [&](int bb, int t) {
    const int kv0 = t * 64;
#pragma unroll
    for (int c = 0; c < 2; ++c) {
      const int p = c * 4 + wv;
      gload_lds16(Kg + (size_t)(kv0 + l) * DIM + hc + p * 8, &Kl[bb][p][0][0]);
      gload_lds16(Vt + (size_t)(hc + l) * SEQ + kv0 + p * 8, &Vl[bb][p][0][0]);
    }
  };

  if (s <= tmaxb) {
    stage(0, s);
    int bb = 0;
#pragma unroll 1
    for (int t = s; t <= tmaxb; t += 4) {
      __syncthreads();                       // stage(t) done; compute(t-4) done
      if (t + 4 <= tmaxb) stage(bb ^ 1, t + 4);
      if (t <= tdiag) {
        const int kv0 = t * 64;
        bf16x8 kf0[4], kf1[4];
#pragma unroll
        for (int ks = 0; ks < 4; ++ks) {
          kf0[ks] = *(const bf16x8*)&Kl[bb][ks * 2 + hi][l31][0];
          kf1[ks] = *(const bf16x8*)&Kl[bb][ks * 2 + hi][32 + l31][0];
        }
        f32x16 s0 = {}, s1 = {};
        __builtin_amdgcn_s_setprio(1);
#pragma unroll
        for (int ks = 0; ks < 4; ++ks) {
          s0 = __builtin_amdgcn_mfma_f32_32x32x16_bf16(kf0[ks], qf[ks], s0, 0, 0, 0);
          s1 = __builtin_amdgcn_mfma_f32_32x32x16_bf16(kf1[ks], qf[ks], s1, 0, 0, 0);
        }
        __builtin_amdgcn_s_setprio(0);
        bf16x8 vf0[4], vf1[4];
#pragma unroll
        for (int k2 = 0; k2 < 4; ++k2) {
          vf0[k2] = *(const bf16x8*)&Vl[bb][k2 * 2 + hi][l31][0];
          vf1[k2] = *(const bf16x8*)&Vl[bb][k2 * 2 + hi][32 + l31][0];
        }
        if (t == tdiag) {
#pragma unroll
          for (int r = 0; r < 16; ++r) {
            const int kp = (r & 3) + 8 * (r >> 2) + 4 * hi;
            if (kv0 + kp      > qg) s0[r] = -1.0e30f;
            if (kv0 + 32 + kp > qg) s1[r] = -1.0e30f;
          }
        }
        // fixed-m softmax: p = exp2(s2), no max tracking (bounded scores)
#pragma unroll
        for (int r = 0; r < 16; ++r) {
          s0[r] = __builtin_exp2f(s0[r]);
          s1[r] = __builtin_exp2f(s1[r]);
        }
#pragma unroll
        for (int r = 0; r < 8; ++r)
          sacc[r] += (s0[r] + s0[r + 8]) + (s1[r] + s1[r + 8]);
        // P^T B-frags: lane sends what its partner needs; one shfl per chan
        __builtin_amdgcn_s_setprio(1);
#pragma unroll
        for (int sub = 0; sub < 2; ++sub) {
#pragma unroll
          for (int hf = 0; hf < 2; ++hf) {
            const int rb = hf * 8;
            float v0, v1, v2, v3, v4, v5, v6, v7;
            if (sub == 0) {
              v0 = s0[rb+0]; v1 = s0[rb+1]; v2 = s0[rb+2]; v3 = s0[rb+3];
              v4 = s0[rb+4]; v5 = s0[rb+5]; v6 = s0[rb+6]; v7 = s0[rb+7];
            } else {
              v0 = s1[rb+0]; v1 = s1[rb+1]; v2 = s1[rb+2]; v3 = s1[rb+3];
              v4 = s1[rb+4]; v5 = s1[rb+5]; v6 = s1[rb+6]; v7 = s1[rb+7];
            }
            const unsigned w0 = pack2(v0, v1), w1 = pack2(v2, v3);
            const unsigned w2 = pack2(v4, v5), w3 = pack2(v6, v7);
            const unsigned sa = hi ? w0 : w2;
            const unsigned sb = hi ? w1 : w3;
            const unsigned ra  = (unsigned)__shfl_xor((int)sa, 32);
            const unsigned rb_ = (unsigned)__shfl_xor((int)sb, 32);
            u32x4 fu;
            fu[0] = hi ? ra  : w0;
            fu[1] = hi ? rb_ : w1;
            fu[2] = hi ? w2  : ra;
            fu[3] = hi ? w3  : rb_;
            const bf16x8 pb = __builtin_bit_cast(bf16x8, fu);
            const int k2 = sub * 2 + hf;
            ot0 = __builtin_amdgcn_mfma_f32_32x32x16_bf16(
                k2 == 0 ? vf0[0] : k2 == 1 ? vf0[1] : k2 == 2 ? vf0[2] : vf0[3],
                pb, ot0, 0, 0, 0);
            ot1 = __builtin_amdgcn_mfma_f32_32x32x16_bf16(
                k2 == 0 ? vf1[0] : k2 == 1 ? vf1[1] : k2 == 2 ? vf1[2] : vf1[3],
                pb, ot1, 0, 0, 0);
          }
        }
        __builtin_amdgcn_s_setprio(0);
      }
      bb ^= 1;
    }
  }

  // epilogue: tree-reduce sum once, cross-half add, write partial + sum
  float sum_ = 0.f;
  {
    float t4[4];
#pragma unroll
    for (int r = 0; r < 4; ++r) t4[r] = sacc[r] + sacc[r + 4];
    sum_ = (t4[0] + t4[1]) + (t4[2] + t4[3]);
    sum_ += __shfl_xor(sum_, 32);
  }
#pragma unroll
  for (int g = 0; g < 4; ++g) {
    bf16x4 o0, o1;
#pragma unroll
    for (int e = 0; e < 4; ++e) {
      o0[e] = (bf16)ot0[g * 4 + e];
      o1[e] = (bf16)ot1[g * 4 + e];
    }
    *(bf16x4*)(Po + (size_t)qg * DIM + hc + g * 8 + hi * 4)      = o0;
    *(bf16x4*)(Po + (size_t)qg * DIM + hc + 32 + g * 8 + hi * 4) = o1;
  }
  if (hi == 0)
    ms[((size_t)s * SEQ + qg) * NH + h] = sum_;
}

// ---------- denominators: invden[q][h] = 1 / sum_s ms[s][q][h] --------------
__global__ __launch_bounds__(256)
void attn_den(const float* __restrict__ ms, float* __restrict__ invden) {
  const int i = blockIdx.x * 256 + threadIdx.x;   // SEQ*NH = 65536
  float d = 0.f;
#pragma unroll
  for (int s = 0; s < 4; ++s) d += ms[(size_t)s * SEQ * NH + i];
  invden[i] = 1.0f / d;
}

// ---- Output GEMM with fused combine: A = (P0+P1+P2+P3)*invden, C = A W^T ----
// 64x128 tile -> grid 512 (2 blocks/CU). A staged via registers (combine),
// B via global_load_lds.
__global__ __launch_bounds__(256, 2)
void gemm_out(const bf16* __restrict__ P0, const bf16* __restrict__ P1,
              const bf16* __restrict__ P2, const bf16* __restrict__ P3,
              const float* __restrict__ invden,
              const bf16* __restrict__ W, float* __restrict__ C) {
  __shared__ bf16 As[64 * 32];
  __shared__ bf16 Bs[128 * 32];
  const int tid = threadIdx.x;
  const int w   = tid >> 6;
  const int l   = tid & 63;
  const int l15 = l & 15, lhi = l >> 4;
  const int wr  = w >> 1, wc = w & 1;
  const int row0 = blockIdx.y * 64;
  const int col0 = blockIdx.x * 128;

  f32x4 acc[2][4] = {};

  const int srowA = w * 16 + (l >> 2);      // 0..63
  const int srowB = w * 32 + (l >> 2);
  const int scol  = (l & 3) * 8;
  const int arow  = row0 + srowA;           // this thread's q-row (fixed)
  const size_t poff = (size_t)arow * DIM + scol;
  const bf16* gB = W + (size_t)(col0 + srowB) * DIM + scol;
  bf16* lA = As + srowA * 32 + scol;
  bf16* lB = Bs + srowB * 32 + scol;

  for (int k0 = 0; k0 < DIM; k0 += 32) {
    __syncthreads();
    gload_lds16(gB + k0,            lB);
    gload_lds16(gB + k0 + 16 * DIM, lB + 16 * 32);
    // fused combine for the A tile slice [arow][k0+scol .. +8)
    {
      const float inv = invden[arow * NH + ((k0 + scol) >> 6)];
      bf16x8 p0 = *(const bf16x8*)(P0 + poff + k0);
      bf16x8 p1 = *(const bf16x8*)(P1 + poff + k0);
      bf16x8 p2 = *(const bf16x8*)(P2 + poff + k0);
      bf16x8 p3 = *(const bf16x8*)(P3 + poff + k0);
      bf16x8 a;
#pragma unroll
      for (int j = 0; j < 8; ++j) {
        const float v = (float)p0[j] + (float)p1[j] + (float)p2[j] + (float)p3[j];
        a[j] = (bf16)(v * inv);
      }
      *(bf16x8*)lA = a;
    }
    __syncthreads();
    bf16x8 af[2], bf_[4];
#pragma unroll
    for (int m = 0; m < 2; ++m)
      af[m] = *(const bf16x8*)(As + (wr * 32 + m * 16 + l15) * 32 + lhi * 8);
#pragma unroll
    for (int n = 0; n < 4; ++n)
      bf_[n] = *(const bf16x8*)(Bs + (wc * 64 + n * 16 + l15) * 32 + lhi * 8);
#pragma unroll
    for (int m = 0; m < 2; ++m)
#pragma unroll
      for (int n = 0; n < 4; ++n)
        acc[m][n] = __builtin_amdgcn_mfma_f32_16x16x32_bf16(af[m], bf_[n], acc[m][n], 0, 0, 0);
  }

#pragma unroll
  for (int m = 0; m < 2; ++m)
#pragma unroll
    for (int n = 0; n < 4; ++n)
#pragma unroll
      for (int r = 0; r < 4; ++r) {
        const int row = row0 + wr * 32 + m * 16 + lhi * 4 + r;
        const int col = col0 + wc * 64 + n * 16 + l15;
        C[(size_t)row * DIM + col] = acc[m][n][r];
      }
}

extern "C" void kernel_launch(void* const* d_in, const int* in_sizes, int n_in,
                              void* d_out, int out_size, void* d_ws, size_t ws_size,
                              hipStream_t stream) {
  const float* x  = (const float*)d_in[0];
  const float* Wq = (const float*)d_in[1];
  const float* Wk = (const float*)d_in[2];
  const float* Wv = (const float*)d_in[3];
  const float* Wo = (const float*)d_in[4];
  float* out = (float*)d_out;

  // ws layout (bf16 elems; ~65.5 MB total):
  // xb/Vt 0..4M | weights 4M..8M | Qs 8M..12M | Ks 12M..16M | Vs 16M..20M
  // (Vs = P0) | P1 20M..24M | P2 24M..28M | P3 28M..32M | ms f32 (1MB) |
  // invden f32 (256KB)
  constexpr size_t MT = (size_t)SEQ * DIM;   // 4M elems
  bf16* xb  = (bf16*)d_ws;
  bf16* wqb = xb  + MT;
  bf16* wkb = wqb + (size_t)DIM * DIM;
  bf16* wvb = wkb + (size_t)DIM * DIM;
  bf16* wob = wvb + (size_t)DIM * DIM;
  bf16* Qs  = wob + (size_t)DIM * DIM;
  bf16* Ks  = Qs  + MT;
  bf16* Vs  = Ks  + MT;
  bf16* P1  = Vs  + MT;
  bf16* P2  = P1  + MT;
  bf16* P3  = P2  + MT;
  float* ms = (float*)(P3 + MT);
  float* invden = ms + (size_t)4 * SEQ * NH;
  bf16* Vt  = xb;   // [DIM][SEQ]
  bf16* P0  = Vs;

  cvt5<<<dim3((SEQ * DIM) / (256 * 8), 5), 256, 0, stream>>>(
      x, Wq, Wk, Wv, Wo, xb, wqb, wkb, wvb, wob);

  gemm_xwt<bf16, true><<<dim3(DIM / 128, SEQ / 128, 3), 256, 0, stream>>>(
      xb, wqb, wkb, wvb, Qs, Ks, Vs);

  transpose_v<<<dim3(SEQ / 64, DIM / 64), 256, 0, stream>>>(Vs, Vt);

  attn_fwd<<<dim3(2048), 256, 0, stream>>>(Qs, Ks, Vt, P0, P1, P2, P3, ms);

  attn_den<<<dim3(SEQ * NH / 256), 256, 0, stream>>>(ms, invden);

  gemm_out<<<dim3(DIM / 128, SEQ / 64), 256, 0, stream>>>(
      P0, P1, P2, P3, invden, wob, out);
}

// Round 15
// 148.939 us; speedup vs baseline: 1.1377x; 1.1377x over previous
//
#include <hip/hip_runtime.h>
#include <hip/hip_bf16.h>
#include <stdint.h>

// B=1, S=4096, D=1024, H=16, HD=64. I/O = float32; internal compute bf16 MFMA.
constexpr int SEQ  = 4096;
constexpr int DIM  = 1024;
constexpr int NH   = 16;
constexpr int HDM  = 64;

typedef __bf16 bf16;
typedef __attribute__((ext_vector_type(4)))  float  f32x4;
typedef __attribute__((ext_vector_type(16))) float  f32x16;
typedef __attribute__((ext_vector_type(8)))  __bf16 bf16x8;
typedef __attribute__((ext_vector_type(4)))  __bf16 bf16x4;
typedef __attribute__((ext_vector_type(4)))  unsigned u32x4;

__device__ __forceinline__ void gload_lds16(const bf16* g, bf16* l) {
  __builtin_amdgcn_global_load_lds(
      (const __attribute__((address_space(1))) unsigned int*)g,
      (__attribute__((address_space(3))) unsigned int*)l, 16, 0, 0);
}

__device__ __forceinline__ unsigned pack2(float lo, float hi) {
  unsigned short a = __builtin_bit_cast(unsigned short, (bf16)lo);
  unsigned short b = __builtin_bit_cast(unsigned short, (bf16)hi);
  return ((unsigned)b << 16) | a;
}

// f32 -> bf16 for x + the 4 weight matrices. blockIdx.y selects tensor.
__global__ void cvt5(const float* __restrict__ x,  const float* __restrict__ wq,
                     const float* __restrict__ wk, const float* __restrict__ wv,
                     const float* __restrict__ wo,
                     bf16* __restrict__ xb,  bf16* __restrict__ wqb,
                     bf16* __restrict__ wkb, bf16* __restrict__ wvb,
                     bf16* __restrict__ wob) {
  const float* in; bf16* out; int n;
  switch (blockIdx.y) {
    case 0:  in = x;  out = xb;  n = SEQ * DIM; break;
    case 1:  in = wq; out = wqb; n = DIM * DIM; break;
    case 2:  in = wk; out = wkb; n = DIM * DIM; break;
    case 3:  in = wv; out = wvb; n = DIM * DIM; break;
    default: in = wo; out = wob; n = DIM * DIM; break;
  }
  const int i = (blockIdx.x * blockDim.x + threadIdx.x) * 8;
  if (i >= n) return;
  f32x4 a = *(const f32x4*)(in + i);
  f32x4 b = *(const f32x4*)(in + i + 4);
  bf16x8 o;
#pragma unroll
  for (int j = 0; j < 4; ++j) { o[j] = (bf16)a[j]; o[j + 4] = (bf16)b[j]; }
  *(bf16x8*)(out + i) = o;
}

// ------------- QKV GEMM: 128x128 tile, C = (A W^T) * sc --------------------
template <typename OutT, bool QKV>
__global__ __launch_bounds__(256, 2)
void gemm_xwt(const bf16* __restrict__ A,
              const bf16* __restrict__ W0, const bf16* __restrict__ W1,
              const bf16* __restrict__ W2,
              OutT* __restrict__ C0, OutT* __restrict__ C1, OutT* __restrict__ C2) {
  const bf16* W;
  OutT* C;
  float sc = 1.0f;
  if (QKV) {
    const int z = blockIdx.z;
    W = (z == 0) ? W0 : (z == 1) ? W1 : W2;
    C = (z == 0) ? C0 : (z == 1) ? C1 : C2;
    if (z == 0) sc = 0.18033688011112042f;  // 0.125 * log2(e)
  } else {
    W = W0; C = C0;
  }
  __shared__ bf16 As[128 * 32];
  __shared__ bf16 Bs[128 * 32];
  const int tid = threadIdx.x;
  const int w   = tid >> 6;
  const int l   = tid & 63;
  const int l15 = l & 15, lhi = l >> 4;
  const int wr  = w >> 1, wc = w & 1;
  const int row0 = blockIdx.y * 128;
  const int col0 = blockIdx.x * 128;

  f32x4 acc[4][4] = {};

  const int srow = w * 32 + (l >> 2);
  const int scol = (l & 3) * 8;
  const bf16* gA = A + (size_t)(row0 + srow) * DIM + scol;
  const bf16* gB = W + (size_t)(col0 + srow) * DIM + scol;
  bf16* lA = As + srow * 32 + scol;
  bf16* lB = Bs + srow * 32 + scol;

  for (int k0 = 0; k0 < DIM; k0 += 32) {
    __syncthreads();
    gload_lds16(gA + k0,            lA);
    gload_lds16(gA + k0 + 16 * DIM, lA + 16 * 32);
    gload_lds16(gB + k0,            lB);
    gload_lds16(gB + k0 + 16 * DIM, lB + 16 * 32);
    __syncthreads();
    bf16x8 af[4], bf_[4];
#pragma unroll
    for (int m = 0; m < 4; ++m)
      af[m] = *(const bf16x8*)(As + (wr * 64 + m * 16 + l15) * 32 + lhi * 8);
#pragma unroll
    for (int n = 0; n < 4; ++n)
      bf_[n] = *(const bf16x8*)(Bs + (wc * 64 + n * 16 + l15) * 32 + lhi * 8);
#pragma unroll
    for (int m = 0; m < 4; ++m)
#pragma unroll
      for (int n = 0; n < 4; ++n)
        acc[m][n] = __builtin_amdgcn_mfma_f32_16x16x32_bf16(af[m], bf_[n], acc[m][n], 0, 0, 0);
  }

#pragma unroll
  for (int m = 0; m < 4; ++m)
#pragma unroll
    for (int n = 0; n < 4; ++n)
#pragma unroll
      for (int r = 0; r < 4; ++r) {
        const int row = row0 + wr * 64 + m * 16 + lhi * 4 + r;
        const int col = col0 + wc * 64 + n * 16 + l15;
        C[(size_t)row * DIM + col] = (OutT)(acc[m][n][r] * sc);
      }
}

// ---- Output GEMM: 64x128 tile -> grid 512 (2 blocks/CU; best measured r13) --
__global__ __launch_bounds__(256, 2)
void gemm_out(const bf16* __restrict__ A, const bf16* __restrict__ W,
              float* __restrict__ C) {
  __shared__ bf16 As[64 * 32];
  __shared__ bf16 Bs[128 * 32];
  const int tid = threadIdx.x;
  const int w   = tid >> 6;
  const int l   = tid & 63;
  const int l15 = l & 15, lhi = l >> 4;
  const int wr  = w >> 1, wc = w & 1;
  const int row0 = blockIdx.y * 64;
  const int col0 = blockIdx.x * 128;

  f32x4 acc[2][4] = {};

  const int srowA = w * 16 + (l >> 2);
  const int srowB = w * 32 + (l >> 2);
  const int scol  = (l & 3) * 8;
  const bf16* gA = A + (size_t)(row0 + srowA) * DIM + scol;
  const bf16* gB = W + (size_t)(col0 + srowB) * DIM + scol;
  bf16* lA = As + srowA * 32 + scol;
  bf16* lB = Bs + srowB * 32 + scol;

  for (int k0 = 0; k0 < DIM; k0 += 32) {
    __syncthreads();
    gload_lds16(gA + k0,            lA);
    gload_lds16(gB + k0,            lB);
    gload_lds16(gB + k0 + 16 * DIM, lB + 16 * 32);
    __syncthreads();
    bf16x8 af[2], bf_[4];
#pragma unroll
    for (int m = 0; m < 2; ++m)
      af[m] = *(const bf16x8*)(As + (wr * 32 + m * 16 + l15) * 32 + lhi * 8);
#pragma unroll
    for (int n = 0; n < 4; ++n)
      bf_[n] = *(const bf16x8*)(Bs + (wc * 64 + n * 16 + l15) * 32 + lhi * 8);
#pragma unroll
    for (int m = 0; m < 2; ++m)
#pragma unroll
      for (int n = 0; n < 4; ++n)
        acc[m][n] = __builtin_amdgcn_mfma_f32_16x16x32_bf16(af[m], bf_[n], acc[m][n], 0, 0, 0);
  }

#pragma unroll
  for (int m = 0; m < 2; ++m)
#pragma unroll
    for (int n = 0; n < 4; ++n)
#pragma unroll
      for (int r = 0; r < 4; ++r) {
        const int row = row0 + wr * 32 + m * 16 + lhi * 4 + r;
        const int col = col0 + wc * 64 + n * 16 + l15;
        C[(size_t)row * DIM + col] = acc[m][n][r];
      }
}

// --------------- V transpose: Vt[d][s] = Vs[s][d]  (once) -------------------
__global__ __launch_bounds__(256)
void transpose_v(const bf16* __restrict__ Vs, bf16* __restrict__ Vt) {
  __shared__ bf16 t[64][72];
  const int st = blockIdx.x * 64;
  const int dt = blockIdx.y * 64;
  const int tid = threadIdx.x;
  const int r  = tid >> 2;
  const int c0 = (tid & 3) * 16;
  bf16x8 a = *(const bf16x8*)(Vs + (size_t)(st + r) * DIM + dt + c0);
  bf16x8 b = *(const bf16x8*)(Vs + (size_t)(st + r) * DIM + dt + c0 + 8);
#pragma unroll
  for (int j = 0; j < 8; ++j) { t[r][c0 + j] = a[j]; t[r][c0 + 8 + j] = b[j]; }
  __syncthreads();
  const int d  = tid >> 2;
  const int s0 = (tid & 3) * 16;
  bf16x8 o1, o2;
#pragma unroll
  for (int j = 0; j < 8; ++j) { o1[j] = t[s0 + j][d]; o2[j] = t[s0 + 8 + j][d]; }
  bf16* dst = Vt + (size_t)(dt + d) * SEQ + st + s0;
  *(bf16x8*)(dst)     = o1;
  *(bf16x8*)(dst + 8) = o2;
}

// ---- Causal flash attention: 4-way inter-block KV split, FIXED-m softmax ----
// r12 body exactly (single accumulators; dual-acc cost occupancy, r13).
__global__ __launch_bounds__(256, 2)
void attn_fwd(const bf16* __restrict__ Qg, const bf16* __restrict__ Kg,
              const bf16* __restrict__ Vt,
              bf16* __restrict__ P0, bf16* __restrict__ P1,
              bf16* __restrict__ P2, bf16* __restrict__ P3,
              float* __restrict__ ms) {
  __shared__ bf16 Kl[2][8][64][8];   // 16 KB
  __shared__ bf16 Vl[2][8][64][8];   // 16 KB
  const int tid = threadIdx.x;
  const int wv  = tid >> 6;
  const int l   = tid & 63;
  const int l31 = l & 31;
  const int hi  = l >> 5;
  const int bid = blockIdx.x;
  const int s   = bid & 3;
  const int bh  = bid >> 2;
  const int b   = 31 - (bh >> 4);        // big q-tiles dispatch first
  const int h   = bh & 15;
  const int qb0 = b * 128;
  const int hc  = h * HDM;
  const int tmaxb = 2 * b + 1;           // block-level last KV tile
  const int tdiag = 2 * b + (wv >> 1);   // this wave's diagonal tile
  const int qg  = qb0 + wv * 32 + l31;
  bf16* Po = (s == 0) ? P0 : (s == 1) ? P1 : (s == 2) ? P2 : P3;

  // Q B-frags (pre-scaled by 0.125*log2e in the Q-GEMM epilogue)
  bf16x8 qf[4];
#pragma unroll
  for (int ks = 0; ks < 4; ++ks)
    qf[ks] = *(const bf16x8*)(Qg + (size_t)qg * DIM + hc + ks * 16 + hi * 8);

  f32x16 ot0 = {}, ot1 = {};
  float sacc[8] = {};

  auto stage = [&](int bb, int t) {
    const int kv0 = t * 64;
#pragma unroll
    for (int c = 0; c < 2; ++c) {
      const int p = c * 4 + wv;
      gload_lds16(Kg + (size_t)(kv0 + l) * DIM + hc + p * 8, &Kl[bb][p][0][0]);
      gload_lds16(Vt + (size_t)(hc + l) * SEQ + kv0 + p * 8, &Vl[bb][p][0][0]);
    }
  };

  if (s <= tmaxb) {
    stage(0, s);
    int bb = 0;
#pragma unroll 1
    for (int t = s; t <= tmaxb; t += 4) {
      __syncthreads();                       // stage(t) done; compute(t-4) done
      if (t + 4 <= tmaxb) stage(bb ^ 1, t + 4);
      if (t <= tdiag) {
        const int kv0 = t * 64;
        bf16x8 kf0[4], kf1[4];
#pragma unroll
        for (int ks = 0; ks < 4; ++ks) {
          kf0[ks] = *(const bf16x8*)&Kl[bb][ks * 2 + hi][l31][0];
          kf1[ks] = *(const bf16x8*)&Kl[bb][ks * 2 + hi][32 + l31][0];
        }
        f32x16 s0 = {}, s1 = {};
        __builtin_amdgcn_s_setprio(1);
#pragma unroll
        for (int ks = 0; ks < 4; ++ks) {
          s0 = __builtin_amdgcn_mfma_f32_32x32x16_bf16(kf0[ks], qf[ks], s0, 0, 0, 0);
          s1 = __builtin_amdgcn_mfma_f32_32x32x16_bf16(kf1[ks], qf[ks], s1, 0, 0, 0);
        }
        __builtin_amdgcn_s_setprio(0);
        bf16x8 vf0[4], vf1[4];
#pragma unroll
        for (int k2 = 0; k2 < 4; ++k2) {
          vf0[k2] = *(const bf16x8*)&Vl[bb][k2 * 2 + hi][l31][0];
          vf1[k2] = *(const bf16x8*)&Vl[bb][k2 * 2 + hi][32 + l31][0];
        }
        if (t == tdiag) {
#pragma unroll
          for (int r = 0; r < 16; ++r) {
            const int kp = (r & 3) + 8 * (r >> 2) + 4 * hi;
            if (kv0 + kp      > qg) s0[r] = -1.0e30f;
            if (kv0 + 32 + kp > qg) s1[r] = -1.0e30f;
          }
        }
        // fixed-m softmax: p = exp2(s2), no max tracking (bounded scores)
#pragma unroll
        for (int r = 0; r < 16; ++r) {
          s0[r] = __builtin_exp2f(s0[r]);
          s1[r] = __builtin_exp2f(s1[r]);
        }
#pragma unroll
        for (int r = 0; r < 8; ++r)
          sacc[r] += (s0[r] + s0[r + 8]) + (s1[r] + s1[r + 8]);
        // P^T B-frags: lane sends what its partner needs; one shfl per chan
        __builtin_amdgcn_s_setprio(1);
#pragma unroll
        for (int sub = 0; sub < 2; ++sub) {
#pragma unroll
          for (int hf = 0; hf < 2; ++hf) {
            const int rb = hf * 8;
            float v0, v1, v2, v3, v4, v5, v6, v7;
            if (sub == 0) {
              v0 = s0[rb+0]; v1 = s0[rb+1]; v2 = s0[rb+2]; v3 = s0[rb+3];
              v4 = s0[rb+4]; v5 = s0[rb+5]; v6 = s0[rb+6]; v7 = s0[rb+7];
            } else {
              v0 = s1[rb+0]; v1 = s1[rb+1]; v2 = s1[rb+2]; v3 = s1[rb+3];
              v4 = s1[rb+4]; v5 = s1[rb+5]; v6 = s1[rb+6]; v7 = s1[rb+7];
            }
            const unsigned w0 = pack2(v0, v1), w1 = pack2(v2, v3);
            const unsigned w2 = pack2(v4, v5), w3 = pack2(v6, v7);
            const unsigned sa = hi ? w0 : w2;
            const unsigned sb = hi ? w1 : w3;
            const unsigned ra  = (unsigned)__shfl_xor((int)sa, 32);
            const unsigned rb_ = (unsigned)__shfl_xor((int)sb, 32);
            u32x4 fu;
            fu[0] = hi ? ra  : w0;
            fu[1] = hi ? rb_ : w1;
            fu[2] = hi ? w2  : ra;
            fu[3] = hi ? w3  : rb_;
            const bf16x8 pb = __builtin_bit_cast(bf16x8, fu);
            const int k2 = sub * 2 + hf;
            ot0 = __builtin_amdgcn_mfma_f32_32x32x16_bf16(
                k2 == 0 ? vf0[0] : k2 == 1 ? vf0[1] : k2 == 2 ? vf0[2] : vf0[3],
                pb, ot0, 0, 0, 0);
            ot1 = __builtin_amdgcn_mfma_f32_32x32x16_bf16(
                k2 == 0 ? vf1[0] : k2 == 1 ? vf1[1] : k2 == 2 ? vf1[2] : vf1[3],
                pb, ot1, 0, 0, 0);
          }
        }
        __builtin_amdgcn_s_setprio(0);
      }
      bb ^= 1;
    }
  }

  // epilogue: tree-reduce sum once, cross-half add, write partial + sum
  float sum_ = 0.f;
  {
    float t4[4];
#pragma unroll
    for (int r = 0; r < 4; ++r) t4[r] = sacc[r] + sacc[r + 4];
    sum_ = (t4[0] + t4[1]) + (t4[2] + t4[3]);
    sum_ += __shfl_xor(sum_, 32);
  }
#pragma unroll
  for (int g = 0; g < 4; ++g) {
    bf16x4 o0, o1;
#pragma unroll
    for (int e = 0; e < 4; ++e) {
      o0[e] = (bf16)ot0[g * 4 + e];
      o1[e] = (bf16)ot1[g * 4 + e];
    }
    *(bf16x4*)(Po + (size_t)qg * DIM + hc + g * 8 + hi * 4)      = o0;
    *(bf16x4*)(Po + (size_t)qg * DIM + hc + 32 + g * 8 + hi * 4) = o1;
  }
  if (hi == 0)
    ms[((size_t)s * SEQ + qg) * NH + h] = sum_;
}

// ---------- combine: At[q][d] = sum_s P_s[q][d] / sum_s sum_s ---------------
__global__ __launch_bounds__(256)
void attn_combine(const bf16* __restrict__ P0, const bf16* __restrict__ P1,
                  const bf16* __restrict__ P2, const bf16* __restrict__ P3,
                  const float* __restrict__ ms, bf16* __restrict__ At) {
  const int idx = blockIdx.x * 256 + threadIdx.x;  // 524288 threads
  const int q  = idx >> 7;
  const int d0 = (idx & 127) * 8;
  const int h  = d0 >> 6;
  float den = 0.f;
#pragma unroll
  for (int s = 0; s < 4; ++s)
    den += ms[((size_t)s * SEQ + q) * NH + h];
  const float inv = 1.0f / den;
  const size_t off = (size_t)q * DIM + d0;
  bf16x8 p0 = *(const bf16x8*)(P0 + off);
  bf16x8 p1 = *(const bf16x8*)(P1 + off);
  bf16x8 p2 = *(const bf16x8*)(P2 + off);
  bf16x8 p3 = *(const bf16x8*)(P3 + off);
  bf16x8 o;
#pragma unroll
  for (int j = 0; j < 8; ++j) {
    const float v = (float)p0[j] + (float)p1[j] + (float)p2[j] + (float)p3[j];
    o[j] = (bf16)(v * inv);
  }
  *(bf16x8*)(At + off) = o;
}

extern "C" void kernel_launch(void* const* d_in, const int* in_sizes, int n_in,
                              void* d_out, int out_size, void* d_ws, size_t ws_size,
                              hipStream_t stream) {
  const float* x  = (const float*)d_in[0];
  const float* Wq = (const float*)d_in[1];
  const float* Wk = (const float*)d_in[2];
  const float* Wv = (const float*)d_in[3];
  const float* Wo = (const float*)d_in[4];
  float* out = (float*)d_out;

  // ws layout (bf16 elems; ~65 MB total):
  // xb/Vt 0..4M | weights 4M..8M | Qs 8M..12M | Ks 12M..16M | Vs 16M..20M
  // (Vs = P0 = At) | P1 20M..24M | P2 24M..28M | P3 28M..32M | ms f32 (1MB)
  constexpr size_t MT = (size_t)SEQ * DIM;   // 4M elems
  bf16* xb  = (bf16*)d_ws;
  bf16* wqb = xb  + MT;
  bf16* wkb = wqb + (size_t)DIM * DIM;
  bf16* wvb = wkb + (size_t)DIM * DIM;
  bf16* wob = wvb + (size_t)DIM * DIM;
  bf16* Qs  = wob + (size_t)DIM * DIM;
  bf16* Ks  = Qs  + MT;
  bf16* Vs  = Ks  + MT;
  bf16* P1  = Vs  + MT;
  bf16* P2  = P1  + MT;
  bf16* P3  = P2  + MT;
  float* ms = (float*)(P3 + MT);
  bf16* Vt  = xb;   // [DIM][SEQ]
  bf16* P0  = Vs;
  bf16* At  = Vs;

  cvt5<<<dim3((SEQ * DIM) / (256 * 8), 5), 256, 0, stream>>>(
      x, Wq, Wk, Wv, Wo, xb, wqb, wkb, wvb, wob);

  gemm_xwt<bf16, true><<<dim3(DIM / 128, SEQ / 128, 3), 256, 0, stream>>>(
      xb, wqb, wkb, wvb, Qs, Ks, Vs);

  transpose_v<<<dim3(SEQ / 64, DIM / 64), 256, 0, stream>>>(Vs, Vt);

  attn_fwd<<<dim3(2048), 256, 0, stream>>>(Qs, Ks, Vt, P0, P1, P2, P3, ms);

  attn_combine<<<dim3((SEQ * DIM / 8) / 256), 256, 0, stream>>>(
      P0, P1, P2, P3, ms, At);

  gemm_out<<<dim3(DIM / 128, SEQ / 64), 256, 0, stream>>>(At, wob, out);
}

// Round 16
// 145.696 us; speedup vs baseline: 1.1630x; 1.0223x over previous
//
#include <hip/hip_runtime.h>
#include <hip/hip_bf16.h>
#include <stdint.h>

// B=1, S=4096, D=1024, H=16, HD=64. I/O = float32; internal compute bf16 MFMA.
constexpr int SEQ  = 4096;
constexpr int DIM  = 1024;
constexpr int NH   = 16;
constexpr int HDM  = 64;

typedef __bf16 bf16;
typedef __attribute__((ext_vector_type(4)))  float  f32x4;
typedef __attribute__((ext_vector_type(16))) float  f32x16;
typedef __attribute__((ext_vector_type(8)))  __bf16 bf16x8;
typedef __attribute__((ext_vector_type(4)))  __bf16 bf16x4;
typedef __attribute__((ext_vector_type(4)))  unsigned u32x4;

__device__ __forceinline__ void gload_lds16(const bf16* g, bf16* l) {
  __builtin_amdgcn_global_load_lds(
      (const __attribute__((address_space(1))) unsigned int*)g,
      (__attribute__((address_space(3))) unsigned int*)l, 16, 0, 0);
}

__device__ __forceinline__ unsigned pack2(float lo, float hi) {
  unsigned short a = __builtin_bit_cast(unsigned short, (bf16)lo);
  unsigned short b = __builtin_bit_cast(unsigned short, (bf16)hi);
  return ((unsigned)b << 16) | a;
}

// f32 -> bf16 for x + the 4 weight matrices. blockIdx.y selects tensor.
__global__ void cvt5(const float* __restrict__ x,  const float* __restrict__ wq,
                     const float* __restrict__ wk, const float* __restrict__ wv,
                     const float* __restrict__ wo,
                     bf16* __restrict__ xb,  bf16* __restrict__ wqb,
                     bf16* __restrict__ wkb, bf16* __restrict__ wvb,
                     bf16* __restrict__ wob) {
  const float* in; bf16* out; int n;
  switch (blockIdx.y) {
    case 0:  in = x;  out = xb;  n = SEQ * DIM; break;
    case 1:  in = wq; out = wqb; n = DIM * DIM; break;
    case 2:  in = wk; out = wkb; n = DIM * DIM; break;
    case 3:  in = wv; out = wvb; n = DIM * DIM; break;
    default: in = wo; out = wob; n = DIM * DIM; break;
  }
  const int i = (blockIdx.x * blockDim.x + threadIdx.x) * 8;
  if (i >= n) return;
  f32x4 a = *(const f32x4*)(in + i);
  f32x4 b = *(const f32x4*)(in + i + 4);
  bf16x8 o;
#pragma unroll
  for (int j = 0; j < 4; ++j) { o[j] = (bf16)a[j]; o[j + 4] = (bf16)b[j]; }
  *(bf16x8*)(out + i) = o;
}

// ------------- QKV GEMM: 128x128 tile, C = (A W^T) * sc --------------------
template <typename OutT, bool QKV>
__global__ __launch_bounds__(256, 2)
void gemm_xwt(const bf16* __restrict__ A,
              const bf16* __restrict__ W0, const bf16* __restrict__ W1,
              const bf16* __restrict__ W2,
              OutT* __restrict__ C0, OutT* __restrict__ C1, OutT* __restrict__ C2) {
  const bf16* W;
  OutT* C;
  float sc = 1.0f;
  if (QKV) {
    const int z = blockIdx.z;
    W = (z == 0) ? W0 : (z == 1) ? W1 : W2;
    C = (z == 0) ? C0 : (z == 1) ? C1 : C2;
    if (z == 0) sc = 0.18033688011112042f;  // 0.125 * log2(e)
  } else {
    W = W0; C = C0;
  }
  __shared__ bf16 As[128 * 32];
  __shared__ bf16 Bs[128 * 32];
  const int tid = threadIdx.x;
  const int w   = tid >> 6;
  const int l   = tid & 63;
  const int l15 = l & 15, lhi = l >> 4;
  const int wr  = w >> 1, wc = w & 1;
  const int row0 = blockIdx.y * 128;
  const int col0 = blockIdx.x * 128;

  f32x4 acc[4][4] = {};

  const int srow = w * 32 + (l >> 2);
  const int scol = (l & 3) * 8;
  const bf16* gA = A + (size_t)(row0 + srow) * DIM + scol;
  const bf16* gB = W + (size_t)(col0 + srow) * DIM + scol;
  bf16* lA = As + srow * 32 + scol;
  bf16* lB = Bs + srow * 32 + scol;

  for (int k0 = 0; k0 < DIM; k0 += 32) {
    __syncthreads();
    gload_lds16(gA + k0,            lA);
    gload_lds16(gA + k0 + 16 * DIM, lA + 16 * 32);
    gload_lds16(gB + k0,            lB);
    gload_lds16(gB + k0 + 16 * DIM, lB + 16 * 32);
    __syncthreads();
    bf16x8 af[4], bf_[4];
#pragma unroll
    for (int m = 0; m < 4; ++m)
      af[m] = *(const bf16x8*)(As + (wr * 64 + m * 16 + l15) * 32 + lhi * 8);
#pragma unroll
    for (int n = 0; n < 4; ++n)
      bf_[n] = *(const bf16x8*)(Bs + (wc * 64 + n * 16 + l15) * 32 + lhi * 8);
#pragma unroll
    for (int m = 0; m < 4; ++m)
#pragma unroll
      for (int n = 0; n < 4; ++n)
        acc[m][n] = __builtin_amdgcn_mfma_f32_16x16x32_bf16(af[m], bf_[n], acc[m][n], 0, 0, 0);
  }

#pragma unroll
  for (int m = 0; m < 4; ++m)
#pragma unroll
    for (int n = 0; n < 4; ++n)
#pragma unroll
      for (int r = 0; r < 4; ++r) {
        const int row = row0 + wr * 64 + m * 16 + lhi * 4 + r;
        const int col = col0 + wc * 64 + n * 16 + l15;
        C[(size_t)row * DIM + col] = (OutT)(acc[m][n][r] * sc);
      }
}

// ---- Output GEMM: 64x128 tile -> grid 512 (2 blocks/CU; best measured r13) --
__global__ __launch_bounds__(256, 2)
void gemm_out(const bf16* __restrict__ A, const bf16* __restrict__ W,
              float* __restrict__ C) {
  __shared__ bf16 As[64 * 32];
  __shared__ bf16 Bs[128 * 32];
  const int tid = threadIdx.x;
  const int w   = tid >> 6;
  const int l   = tid & 63;
  const int l15 = l & 15, lhi = l >> 4;
  const int wr  = w >> 1, wc = w & 1;
  const int row0 = blockIdx.y * 64;
  const int col0 = blockIdx.x * 128;

  f32x4 acc[2][4] = {};

  const int srowA = w * 16 + (l >> 2);
  const int srowB = w * 32 + (l >> 2);
  const int scol  = (l & 3) * 8;
  const bf16* gA = A + (size_t)(row0 + srowA) * DIM + scol;
  const bf16* gB = W + (size_t)(col0 + srowB) * DIM + scol;
  bf16* lA = As + srowA * 32 + scol;
  bf16* lB = Bs + srowB * 32 + scol;

  for (int k0 = 0; k0 < DIM; k0 += 32) {
    __syncthreads();
    gload_lds16(gA + k0,            lA);
    gload_lds16(gB + k0,            lB);
    gload_lds16(gB + k0 + 16 * DIM, lB + 16 * 32);
    __syncthreads();
    bf16x8 af[2], bf_[4];
#pragma unroll
    for (int m = 0; m < 2; ++m)
      af[m] = *(const bf16x8*)(As + (wr * 32 + m * 16 + l15) * 32 + lhi * 8);
#pragma unroll
    for (int n = 0; n < 4; ++n)
      bf_[n] = *(const bf16x8*)(Bs + (wc * 64 + n * 16 + l15) * 32 + lhi * 8);
#pragma unroll
    for (int m = 0; m < 2; ++m)
#pragma unroll
      for (int n = 0; n < 4; ++n)
        acc[m][n] = __builtin_amdgcn_mfma_f32_16x16x32_bf16(af[m], bf_[n], acc[m][n], 0, 0, 0);
  }

#pragma unroll
  for (int m = 0; m < 2; ++m)
#pragma unroll
    for (int n = 0; n < 4; ++n)
#pragma unroll
      for (int r = 0; r < 4; ++r) {
        const int row = row0 + wr * 32 + m * 16 + lhi * 4 + r;
        const int col = col0 + wc * 64 + n * 16 + l15;
        C[(size_t)row * DIM + col] = acc[m][n][r];
      }
}

// --------------- V transpose: Vt[d][s] = Vs[s][d]  (once) -------------------
__global__ __launch_bounds__(256)
void transpose_v(const bf16* __restrict__ Vs, bf16* __restrict__ Vt) {
  __shared__ bf16 t[64][72];
  const int st = blockIdx.x * 64;
  const int dt = blockIdx.y * 64;
  const int tid = threadIdx.x;
  const int r  = tid >> 2;
  const int c0 = (tid & 3) * 16;
  bf16x8 a = *(const bf16x8*)(Vs + (size_t)(st + r) * DIM + dt + c0);
  bf16x8 b = *(const bf16x8*)(Vs + (size_t)(st + r) * DIM + dt + c0 + 8);
#pragma unroll
  for (int j = 0; j < 8; ++j) { t[r][c0 + j] = a[j]; t[r][c0 + 8 + j] = b[j]; }
  __syncthreads();
  const int d  = tid >> 2;
  const int s0 = (tid & 3) * 16;
  bf16x8 o1, o2;
#pragma unroll
  for (int j = 0; j < 8; ++j) { o1[j] = t[s0 + j][d]; o2[j] = t[s0 + 8 + j][d]; }
  bf16* dst = Vt + (size_t)(dt + d) * SEQ + st + s0;
  *(bf16x8*)(dst)     = o1;
  *(bf16x8*)(dst + 8) = o2;
}

// ---- Causal flash attention: 4-way inter-block KV split, FIXED-m softmax ----
// SINGLE-buffered LDS (16KB vs 32KB dbuf): prefetch gave intra-block overlap
// but halved inter-block residency; at 5 blocks/CU the other blocks' compute
// covers staging latency (m114 implicit overlap). Two barriers per tile.
__global__ __launch_bounds__(256, 2)
void attn_fwd(const bf16* __restrict__ Qg, const bf16* __restrict__ Kg,
              const bf16* __restrict__ Vt,
              bf16* __restrict__ P0, bf16* __restrict__ P1,
              bf16* __restrict__ P2, bf16* __restrict__ P3,
              float* __restrict__ ms) {
  __shared__ bf16 Kl[8][64][8];   // 8 KB
  __shared__ bf16 Vl[8][64][8];   // 8 KB
  const int tid = threadIdx.x;
  const int wv  = tid >> 6;
  const int l   = tid & 63;
  const int l31 = l & 31;
  const int hi  = l >> 5;
  const int bid = blockIdx.x;
  const int s   = bid & 3;
  const int bh  = bid >> 2;
  const int b   = 31 - (bh >> 4);        // big q-tiles dispatch first
  const int h   = bh & 15;
  const int qb0 = b * 128;
  const int hc  = h * HDM;
  const int tmaxb = 2 * b + 1;           // block-level last KV tile
  const int tdiag = 2 * b + (wv >> 1);   // this wave's diagonal tile
  const int qg  = qb0 + wv * 32 + l31;
  bf16* Po = (s == 0) ? P0 : (s == 1) ? P1 : (s == 2) ? P2 : P3;

  // Q B-frags (pre-scaled by 0.125*log2e in the Q-GEMM epilogue)
  bf16x8 qf[4];
#pragma unroll
  for (int ks = 0; ks < 4; ++ks)
    qf[ks] = *(const bf16x8*)(Qg + (size_t)qg * DIM + hc + ks * 16 + hi * 8);

  f32x16 ot0 = {}, ot1 = {};
  float sacc[8] = {};

  auto stage = [&](int t) {
    const int kv0 = t * 64;
#pragma unroll
    for (int c = 0; c < 2; ++c) {
      const int p = c * 4 + wv;
      gload_lds16(Kg + (size_t)(kv0 + l) * DIM + hc + p * 8, &Kl[p][0][0]);
      gload_lds16(Vt + (size_t)(hc + l) * SEQ + kv0 + p * 8, &Vl[p][0][0]);
    }
  };

  if (s <= tmaxb) {
#pragma unroll 1
    for (int t = s; t <= tmaxb; t += 4) {
      stage(t);              // prev compute done (barrier at end of prev iter)
      __syncthreads();       // staging landed
      if (t <= tdiag) {
        const int kv0 = t * 64;
        bf16x8 kf0[4], kf1[4];
#pragma unroll
        for (int ks = 0; ks < 4; ++ks) {
          kf0[ks] = *(const bf16x8*)&Kl[ks * 2 + hi][l31][0];
          kf1[ks] = *(const bf16x8*)&Kl[ks * 2 + hi][32 + l31][0];
        }
        f32x16 s0 = {}, s1 = {};
        __builtin_amdgcn_s_setprio(1);
#pragma unroll
        for (int ks = 0; ks < 4; ++ks) {
          s0 = __builtin_amdgcn_mfma_f32_32x32x16_bf16(kf0[ks], qf[ks], s0, 0, 0, 0);
          s1 = __builtin_amdgcn_mfma_f32_32x32x16_bf16(kf1[ks], qf[ks], s1, 0, 0, 0);
        }
        __builtin_amdgcn_s_setprio(0);
        bf16x8 vf0[4], vf1[4];
#pragma unroll
        for (int k2 = 0; k2 < 4; ++k2) {
          vf0[k2] = *(const bf16x8*)&Vl[k2 * 2 + hi][l31][0];
          vf1[k2] = *(const bf16x8*)&Vl[k2 * 2 + hi][32 + l31][0];
        }
        if (t == tdiag) {
#pragma unroll
          for (int r = 0; r < 16; ++r) {
            const int kp = (r & 3) + 8 * (r >> 2) + 4 * hi;
            if (kv0 + kp      > qg) s0[r] = -1.0e30f;
            if (kv0 + 32 + kp > qg) s1[r] = -1.0e30f;
          }
        }
        // fixed-m softmax: p = exp2(s2), no max tracking (bounded scores)
#pragma unroll
        for (int r = 0; r < 16; ++r) {
          s0[r] = __builtin_exp2f(s0[r]);
          s1[r] = __builtin_exp2f(s1[r]);
        }
#pragma unroll
        for (int r = 0; r < 8; ++r)
          sacc[r] += (s0[r] + s0[r + 8]) + (s1[r] + s1[r + 8]);
        // P^T B-frags: lane sends what its partner needs; one shfl per chan
        __builtin_amdgcn_s_setprio(1);
#pragma unroll
        for (int sub = 0; sub < 2; ++sub) {
#pragma unroll
          for (int hf = 0; hf < 2; ++hf) {
            const int rb = hf * 8;
            float v0, v1, v2, v3, v4, v5, v6, v7;
            if (sub == 0) {
              v0 = s0[rb+0]; v1 = s0[rb+1]; v2 = s0[rb+2]; v3 = s0[rb+3];
              v4 = s0[rb+4]; v5 = s0[rb+5]; v6 = s0[rb+6]; v7 = s0[rb+7];
            } else {
              v0 = s1[rb+0]; v1 = s1[rb+1]; v2 = s1[rb+2]; v3 = s1[rb+3];
              v4 = s1[rb+4]; v5 = s1[rb+5]; v6 = s1[rb+6]; v7 = s1[rb+7];
            }
            const unsigned w0 = pack2(v0, v1), w1 = pack2(v2, v3);
            const unsigned w2 = pack2(v4, v5), w3 = pack2(v6, v7);
            const unsigned sa = hi ? w0 : w2;
            const unsigned sb = hi ? w1 : w3;
            const unsigned ra  = (unsigned)__shfl_xor((int)sa, 32);
            const unsigned rb_ = (unsigned)__shfl_xor((int)sb, 32);
            u32x4 fu;
            fu[0] = hi ? ra  : w0;
            fu[1] = hi ? rb_ : w1;
            fu[2] = hi ? w2  : ra;
            fu[3] = hi ? w3  : rb_;
            const bf16x8 pb = __builtin_bit_cast(bf16x8, fu);
            const int k2 = sub * 2 + hf;
            ot0 = __builtin_amdgcn_mfma_f32_32x32x16_bf16(
                k2 == 0 ? vf0[0] : k2 == 1 ? vf0[1] : k2 == 2 ? vf0[2] : vf0[3],
                pb, ot0, 0, 0, 0);
            ot1 = __builtin_amdgcn_mfma_f32_32x32x16_bf16(
                k2 == 0 ? vf1[0] : k2 == 1 ? vf1[1] : k2 == 2 ? vf1[2] : vf1[3],
                pb, ot1, 0, 0, 0);
          }
        }
        __builtin_amdgcn_s_setprio(0);
      }
      __syncthreads();       // compute done before next stage overwrites
    }
  }

  // epilogue: tree-reduce sum once, cross-half add, write partial + sum
  float sum_ = 0.f;
  {
    float t4[4];
#pragma unroll
    for (int r = 0; r < 4; ++r) t4[r] = sacc[r] + sacc[r + 4];
    sum_ = (t4[0] + t4[1]) + (t4[2] + t4[3]);
    sum_ += __shfl_xor(sum_, 32);
  }
#pragma unroll
  for (int g = 0; g < 4; ++g) {
    bf16x4 o0, o1;
#pragma unroll
    for (int e = 0; e < 4; ++e) {
      o0[e] = (bf16)ot0[g * 4 + e];
      o1[e] = (bf16)ot1[g * 4 + e];
    }
    *(bf16x4*)(Po + (size_t)qg * DIM + hc + g * 8 + hi * 4)      = o0;
    *(bf16x4*)(Po + (size_t)qg * DIM + hc + 32 + g * 8 + hi * 4) = o1;
  }
  if (hi == 0)
    ms[((size_t)s * SEQ + qg) * NH + h] = sum_;
}

// ---------- combine: At[q][d] = sum_s P_s[q][d] / sum_s sum_s ---------------
__global__ __launch_bounds__(256)
void attn_combine(const bf16* __restrict__ P0, const bf16* __restrict__ P1,
                  const bf16* __restrict__ P2, const bf16* __restrict__ P3,
                  const float* __restrict__ ms, bf16* __restrict__ At) {
  const int idx = blockIdx.x * 256 + threadIdx.x;  // 524288 threads
  const int q  = idx >> 7;
  const int d0 = (idx & 127) * 8;
  const int h  = d0 >> 6;
  float den = 0.f;
#pragma unroll
  for (int s = 0; s < 4; ++s)
    den += ms[((size_t)s * SEQ + q) * NH + h];
  const float inv = 1.0f / den;
  const size_t off = (size_t)q * DIM + d0;
  bf16x8 p0 = *(const bf16x8*)(P0 + off);
  bf16x8 p1 = *(const bf16x8*)(P1 + off);
  bf16x8 p2 = *(const bf16x8*)(P2 + off);
  bf16x8 p3 = *(const bf16x8*)(P3 + off);
  bf16x8 o;
#pragma unroll
  for (int j = 0; j < 8; ++j) {
    const float v = (float)p0[j] + (float)p1[j] + (float)p2[j] + (float)p3[j];
    o[j] = (bf16)(v * inv);
  }
  *(bf16x8*)(At + off) = o;
}

extern "C" void kernel_launch(void* const* d_in, const int* in_sizes, int n_in,
                              void* d_out, int out_size, void* d_ws, size_t ws_size,
                              hipStream_t stream) {
  const float* x  = (const float*)d_in[0];
  const float* Wq = (const float*)d_in[1];
  const float* Wk = (const float*)d_in[2];
  const float* Wv = (const float*)d_in[3];
  const float* Wo = (const float*)d_in[4];
  float* out = (float*)d_out;

  // ws layout (bf16 elems; ~65 MB total):
  // xb/Vt 0..4M | weights 4M..8M | Qs 8M..12M | Ks 12M..16M | Vs 16M..20M
  // (Vs = P0 = At) | P1 20M..24M | P2 24M..28M | P3 28M..32M | ms f32 (1MB)
  constexpr size_t MT = (size_t)SEQ * DIM;   // 4M elems
  bf16* xb  = (bf16*)d_ws;
  bf16* wqb = xb  + MT;
  bf16* wkb = wqb + (size_t)DIM * DIM;
  bf16* wvb = wkb + (size_t)DIM * DIM;
  bf16* wob = wvb + (size_t)DIM * DIM;
  bf16* Qs  = wob + (size_t)DIM * DIM;
  bf16* Ks  = Qs  + MT;
  bf16* Vs  = Ks  + MT;
  bf16* P1  = Vs  + MT;
  bf16* P2  = P1  + MT;
  bf16* P3  = P2  + MT;
  float* ms = (float*)(P3 + MT);
  bf16* Vt  = xb;   // [DIM][SEQ]
  bf16* P0  = Vs;
  bf16* At  = Vs;

  cvt5<<<dim3((SEQ * DIM) / (256 * 8), 5), 256, 0, stream>>>(
      x, Wq, Wk, Wv, Wo, xb, wqb, wkb, wvb, wob);

  gemm_xwt<bf16, true><<<dim3(DIM / 128, SEQ / 128, 3), 256, 0, stream>>>(
      xb, wqb, wkb, wvb, Qs, Ks, Vs);

  transpose_v<<<dim3(SEQ / 64, DIM / 64), 256, 0, stream>>>(Vs, Vt);

  attn_fwd<<<dim3(2048), 256, 0, stream>>>(Qs, Ks, Vt, P0, P1, P2, P3, ms);

  attn_combine<<<dim3((SEQ * DIM / 8) / 256), 256, 0, stream>>>(
      P0, P1, P2, P3, ms, At);

  gemm_out<<<dim3(DIM / 128, SEQ / 64), 256, 0, stream>>>(At, wob, out);
}